// Round 6
// baseline (541.825 us; speedup 1.0000x reference)
//
#include <hip/hip_runtime.h>
#include <cstdint>
#include <math.h>

#define S_LEN 2048
#define BATCH 2
#define HID   2048
#define NHEAD 16
#define DHEAD 128

typedef _Float16 h8 __attribute__((ext_vector_type(8)));
typedef _Float16 h4 __attribute__((ext_vector_type(4)));
typedef float f32x4 __attribute__((ext_vector_type(4)));

// async global->LDS, 16B per lane; LDS dest = wave-uniform base + lane*16
__device__ __forceinline__ void gload16(const void* g, void* l) {
  __builtin_amdgcn_global_load_lds(
      (const __attribute__((address_space(1))) unsigned int*)g,
      (__attribute__((address_space(3))) unsigned int*)l, 16, 0, 0);
}

// ---------------------------------------------------------------------------
// fp16 MFMA GEMM (unchanged since R4): C[M,N] = A[M,K] @ Bt[N,K]^T (+bias).
// ---------------------------------------------------------------------------
template <bool HAS_BIAS, bool OUT_HALF>
__global__ __launch_bounds__(256) void gemm_mfma(
    const _Float16* __restrict__ A, const _Float16* __restrict__ Bt,
    const float* __restrict__ bias, void* __restrict__ Cout, int M, int N,
    int K) {
  __shared__ _Float16 As[128 * 32];
  __shared__ _Float16 Bs[128 * 32];
  const int tid = threadIdx.x;
  const int wave = tid >> 6, lane = tid & 63;
  const int ln = lane & 15, quad = lane >> 4;
  const int wm = wave & 1, wn = wave >> 1;
  const int bm = blockIdx.y * 128, bn = blockIdx.x * 128;

  const int sr = lane >> 2;
  const int sk = (lane & 3) * 8;
  const _Float16* ga0 = A + (size_t)(bm + 32 * wave + sr) * K + sk;
  const _Float16* ga1 = A + (size_t)(bm + 32 * wave + 16 + sr) * K + sk;
  const _Float16* gb0 = Bt + (size_t)(bn + 32 * wave + sr) * K + sk;
  const _Float16* gb1 = Bt + (size_t)(bn + 32 * wave + 16 + sr) * K + sk;
  _Float16* la0 = As + 1024 * wave;
  _Float16* la1 = As + 1024 * wave + 512;
  _Float16* lb0 = Bs + 1024 * wave;
  _Float16* lb1 = Bs + 1024 * wave + 512;

  f32x4 acc[4][4];
#pragma unroll
  for (int i = 0; i < 4; i++)
#pragma unroll
    for (int j = 0; j < 4; j++) acc[i][j] = (f32x4){0.f, 0.f, 0.f, 0.f};

  for (int kt = 0; kt < K; kt += 32) {
    __syncthreads();
    gload16(ga0 + kt, la0);
    gload16(ga1 + kt, la1);
    gload16(gb0 + kt, lb0);
    gload16(gb1 + kt, lb1);
    __syncthreads();

    h8 af[4], bf[4];
#pragma unroll
    for (int mt = 0; mt < 4; mt++)
      af[mt] = *(const h8*)&As[(wm * 64 + mt * 16 + ln) * 32 + quad * 8];
#pragma unroll
    for (int nt = 0; nt < 4; nt++)
      bf[nt] = *(const h8*)&Bs[(wn * 64 + nt * 16 + ln) * 32 + quad * 8];
#pragma unroll
    for (int mt = 0; mt < 4; mt++)
#pragma unroll
      for (int nt = 0; nt < 4; nt++)
        acc[mt][nt] = __builtin_amdgcn_mfma_f32_16x16x32_f16(
            af[mt], bf[nt], acc[mt][nt], 0, 0, 0);
  }

#pragma unroll
  for (int mt = 0; mt < 4; mt++) {
#pragma unroll
    for (int r = 0; r < 4; r++) {
      const size_t row = (size_t)(bm + wm * 64 + mt * 16 + quad * 4 + r);
#pragma unroll
      for (int nt = 0; nt < 4; nt++) {
        const int col = bn + wn * 64 + nt * 16 + ln;
        float v = acc[mt][nt][r];
        if (HAS_BIAS) v += bias[col];
        if (OUT_HALF)
          ((_Float16*)Cout)[row * N + col] = (_Float16)v;
        else
          ((float*)Cout)[row * N + col] = v;
      }
    }
  }
}

__global__ __launch_bounds__(256) void transpose_cvt(
    const float* __restrict__ in, _Float16* __restrict__ out, int K, int N) {
  __shared__ float t[64][65];
  const int bn = blockIdx.x * 64, bk = blockIdx.y * 64;
  const int l = threadIdx.x & 63, g = threadIdx.x >> 6;
#pragma unroll
  for (int i = 0; i < 16; i++) {
    int r = g + 4 * i;
    t[r][l] = in[(size_t)(bk + r) * N + bn + l];
  }
  __syncthreads();
#pragma unroll
  for (int i = 0; i < 16; i++) {
    int r = g + 4 * i;
    out[(size_t)(bn + r) * K + bk + l] = (_Float16)t[l][r];
  }
}

__global__ __launch_bounds__(256) void cvt_fp16(const float* __restrict__ in,
                                                _Float16* __restrict__ out,
                                                int n4) {
  int i = blockIdx.x * blockDim.x + threadIdx.x;
  if (i < n4) {
    float4 v = ((const float4*)in)[i];
    h4 o = {(_Float16)v.x, (_Float16)v.y, (_Float16)v.z, (_Float16)v.w};
    *(h4*)&out[4 * (size_t)i] = o;
  }
}

// ---------------------------------------------------------------------------
// V pre-transpose: mixed [s][b][nh][384] (V at +256) -> Vtg [b*nh][d][s] fp16.
// 64(s) x 64(d) tiles; grid (S/64, D/64, B*NH), 256 thr.
// ---------------------------------------------------------------------------
__global__ __launch_bounds__(256) void transpose_v(
    const _Float16* __restrict__ mixed, _Float16* __restrict__ Vtg) {
  __shared__ _Float16 T[64 * 72];  // [d][s], stride 72 halves (144B)
  const int sb = blockIdx.x * 64;
  const int db = blockIdx.y * 64;
  const int z = blockIdx.z;  // b*NH + h
  const int tid = threadIdx.x;

  // read: 64 s-rows x 64 d halves; thread: row r=tid>>2, d chunk (tid&3)*16
  const int r = tid >> 2, d0 = (tid & 3) * 16;
  {
    const _Float16* src =
        mixed + ((size_t)(sb + r) * (BATCH * NHEAD) + z) * 384 + 256 + db + d0;
    h8 v0 = *(const h8*)src;
    h8 v1 = *(const h8*)(src + 8);
#pragma unroll
    for (int e = 0; e < 8; e++) T[(d0 + e) * 72 + r] = v0[e];
#pragma unroll
    for (int e = 0; e < 8; e++) T[(d0 + 8 + e) * 72 + r] = v1[e];
  }
  __syncthreads();
  // write: 64 d-rows x 64 s halves; thread: d-row tid>>2, s chunk (tid&3)*16
  {
    const int dl = tid >> 2, s0 = (tid & 3) * 16;
    h8 v0 = *(const h8*)&T[dl * 72 + s0];
    h8 v1 = *(const h8*)&T[dl * 72 + s0 + 8];
    _Float16* dst = Vtg + ((size_t)z * DHEAD + db + dl) * S_LEN + sb + s0;
    *(h8*)dst = v0;
    *(h8*)(dst + 8) = v1;
  }
}

// ---------------------------------------------------------------------------
// fp16-MFMA flash attention v4. Grid (S/128, NH, B), 256 thr (4 waves).
// R6 changes vs v3:
//  - Q-tile 128; wave owns 32 q-rows (2 m-frags): reads-per-FLOP -40%
//  - Q A-frags in REGISTERS (loaded once, pre-scaled): Qs gone from LDS
//  - V staged from pre-transposed global Vtg -> all-b128 staging, no
//    scalar transposed writes (R5's 2.55e7 bank conflicts)
//  - no-max softmax (R5-proven): p=exp(s), masked -> exp(-1e4)=0; single
//    end reduction of l.
// LDS: Ks 64x136 (17408B) + Vt 128x72 (18432B) + St 4x32x72 (18432B)
//    = 54,272 B -> 2 blocks/CU.
// ---------------------------------------------------------------------------
__global__ __launch_bounds__(256) void flash_attn_v4(
    const _Float16* __restrict__ mixed, const _Float16* __restrict__ Vtg,
    const unsigned char* __restrict__ mask, _Float16* __restrict__ ctx) {
  const int qt = (int)gridDim.x - 1 - (int)blockIdx.x;  // big blocks first
  const int h = blockIdx.y, b = blockIdx.z;
  const int qb = qt * 128;
  const int tid = threadIdx.x;
  const int wave = tid >> 6, lane = tid & 63;
  const int ln = lane & 15, quad = lane >> 4;

  __shared__ _Float16 Ks[64 * 136];
  __shared__ _Float16 Vt[128 * 72];    // [d][k]
  __shared__ _Float16 St[4][32 * 72];  // per-wave P [m=32][k=64]

  const size_t RS = (size_t)BATCH * NHEAD * 384;  // halves per seq row
  const _Float16* base = mixed + ((size_t)b * NHEAD + h) * 384;
  const _Float16* vbase = Vtg + (size_t)(b * NHEAD + h) * DHEAD * S_LEN;
  const unsigned char* mbase = mask + (size_t)b * S_LEN * S_LEN;
  const float scale = 0.08838834764831845f;  // 1/sqrt(128)

  // ---- Q fragments -> registers (scaled). qfrag[mt][kq] ----
  h8 qfrag[2][4];
#pragma unroll
  for (int mt = 0; mt < 2; mt++) {
    const size_t row = (size_t)(qb + 32 * wave + 16 * mt + ln);
#pragma unroll
    for (int kq = 0; kq < 4; kq++) {
      h8 v = *(const h8*)(base + row * RS + 32 * kq + 8 * quad);
#pragma unroll
      for (int j = 0; j < 8; j++) v[j] = (_Float16)((float)v[j] * scale);
      qfrag[mt][kq] = v;
    }
  }

  f32x4 o[2][8];
#pragma unroll
  for (int mt = 0; mt < 2; mt++)
#pragma unroll
    for (int nt = 0; nt < 8; nt++) o[mt][nt] = (f32x4){0.f, 0.f, 0.f, 0.f};
  float lpart[2][4] = {{0.f, 0.f, 0.f, 0.f}, {0.f, 0.f, 0.f, 0.f}};

  const int ntiles = 2 * qt + 2;  // K-tiles of 64

  for (int kt = 0; kt < ntiles; kt++) {
    const int kb = kt * 64;
    __syncthreads();  // B1: prev tile's readers done

    // ---- stage K rows (b128 both sides) ----
    {
      const int srow = tid >> 2, d0 = (tid & 3) * 8;
#pragma unroll
      for (int i = 0; i < 4; i++)
        *(h8*)&Ks[srow * 136 + d0 + 32 * i] =
            *(const h8*)(base + (size_t)(kb + srow) * RS + 128 + d0 + 32 * i);
    }
    // ---- stage Vt rows from pre-transposed global (b128 both sides) ----
    {
      const int d = tid >> 1, k0 = (tid & 1) * 32;
      const _Float16* src = vbase + (size_t)d * S_LEN + kb + k0;
#pragma unroll
      for (int i = 0; i < 4; i++)
        *(h8*)&Vt[d * 72 + k0 + 8 * i] = *(const h8*)(src + 8 * i);
    }
    __syncthreads();  // B2: tiles staged

    // mask bytes
    unsigned char mreg[2][4][4];
#pragma unroll
    for (int mt = 0; mt < 2; mt++)
#pragma unroll
      for (int r = 0; r < 4; r++)
#pragma unroll
        for (int jn = 0; jn < 4; jn++)
          mreg[mt][r][jn] =
              mbase[(size_t)(qb + 32 * wave + 16 * mt + 4 * quad + r) * S_LEN +
                    kb + 16 * jn + ln];

    // ---- QK^T: B-frag read once, reused across both m-frags ----
    f32x4 s[2][4];
#pragma unroll
    for (int mt = 0; mt < 2; mt++)
#pragma unroll
      for (int jn = 0; jn < 4; jn++) s[mt][jn] = (f32x4){0.f, 0.f, 0.f, 0.f};
#pragma unroll
    for (int kq = 0; kq < 4; kq++) {
#pragma unroll
      for (int jn = 0; jn < 4; jn++) {
        h8 bk = *(const h8*)&Ks[(16 * jn + ln) * 136 + 32 * kq + 8 * quad];
#pragma unroll
        for (int mt = 0; mt < 2; mt++)
          s[mt][jn] = __builtin_amdgcn_mfma_f32_16x16x32_f16(
              qfrag[mt][kq], bk, s[mt][jn], 0, 0, 0);
      }
    }

    // ---- no-max softmax ----
#pragma unroll
    for (int mt = 0; mt < 2; mt++)
#pragma unroll
      for (int jn = 0; jn < 4; jn++)
#pragma unroll
        for (int r = 0; r < 4; r++) {
          const int grow = qb + 32 * wave + 16 * mt + 4 * quad + r;
          const int gcol = kb + 16 * jn + ln;
          const float sv =
              ((gcol > grow) || mreg[mt][r][jn]) ? -10000.0f : s[mt][jn][r];
          const float p = __expf(sv);
          lpart[mt][r] += p;
          St[wave][(16 * mt + 4 * quad + r) * 72 + 16 * jn + ln] = (_Float16)p;
        }
    __threadfence_block();

    // ---- PV: V-frag read once, reused across both m-frags ----
#pragma unroll
    for (int kq2 = 0; kq2 < 2; kq2++) {
      h8 ap[2];
#pragma unroll
      for (int mt = 0; mt < 2; mt++)
        ap[mt] = *(const h8*)&St[wave][(16 * mt + ln) * 72 + 32 * kq2 + 8 * quad];
#pragma unroll
      for (int nt = 0; nt < 8; nt++) {
        h8 bv = *(const h8*)&Vt[(16 * nt + ln) * 72 + 32 * kq2 + 8 * quad];
#pragma unroll
        for (int mt = 0; mt < 2; mt++)
          o[mt][nt] = __builtin_amdgcn_mfma_f32_16x16x32_f16(ap[mt], bv,
                                                             o[mt][nt], 0, 0, 0);
      }
    }
  }

  // ---- epilogue ----
#pragma unroll
  for (int mt = 0; mt < 2; mt++)
#pragma unroll
    for (int r = 0; r < 4; r++) {
      float l = lpart[mt][r];
#pragma unroll
      for (int off = 8; off >= 1; off >>= 1) l += __shfl_xor(l, off, 16);
      const float inv_l = 1.0f / l;
      const size_t row_g = (size_t)(qb + 32 * wave + 16 * mt + 4 * quad + r);
      _Float16* dst = ctx + (row_g * BATCH + b) * HID + h * DHEAD;
#pragma unroll
      for (int nt = 0; nt < 8; nt++)
        dst[16 * nt + ln] = (_Float16)(o[mt][nt][r] * inv_l);
    }
}

__global__ void copy_bias(const float* __restrict__ src,
                          float* __restrict__ dst) {
  int i = blockIdx.x * blockDim.x + threadIdx.x;
  if (i < HID) dst[i] = src[i];
}

extern "C" void kernel_launch(void* const* d_in, const int* in_sizes, int n_in,
                              void* d_out, int out_size, void* d_ws,
                              size_t ws_size, hipStream_t stream) {
  (void)in_sizes;
  (void)n_in;
  const float* hs = (const float*)d_in[0];
  const unsigned char* mask = (const unsigned char*)d_in[1];
  const float* qkv_w = (const float*)d_in[2];
  const float* qkv_b = (const float*)d_in[3];
  const float* proj_w = (const float*)d_in[4];
  const float* proj_b = (const float*)d_in[5];
  float* out = (float*)d_out;

  const size_t M = (size_t)S_LEN * BATCH;
  const size_t mixed_e = M * 3 * HID;            // 25.17M
  const size_t qkvwt_e = (size_t)3 * HID * HID;  // 12.58M
  const size_t hsh_e = M * HID;                  // 8.39M
  const size_t projwt_e = (size_t)HID * HID;     // 4.19M
  const size_t ctx_e = M * HID;                  // 8.39M
  const size_t vtg_e = (size_t)BATCH * NHEAD * DHEAD * S_LEN;  // 8.39M
  const size_t need =
      (mixed_e + qkvwt_e + hsh_e + projwt_e + ctx_e + vtg_e) * sizeof(_Float16);
  if (ws_size < need) return;  // 134,217,728 B == R1-proven floor

  _Float16* mixed = (_Float16*)d_ws;
  _Float16* qkv_wt = mixed + mixed_e;
  _Float16* hs_h = qkv_wt + qkvwt_e;
  _Float16* proj_wt = hs_h + hsh_e;
  _Float16* ctx = proj_wt + projwt_e;
  _Float16* vtg = ctx + ctx_e;

  cvt_fp16<<<(int)(hsh_e / 4 / 256), 256, 0, stream>>>(hs, hs_h,
                                                       (int)(hsh_e / 4));
  transpose_cvt<<<dim3(3 * HID / 64, HID / 64), 256, 0, stream>>>(
      qkv_w, qkv_wt, HID, 3 * HID);
  transpose_cvt<<<dim3(HID / 64, HID / 64), 256, 0, stream>>>(
      proj_w, proj_wt, HID, HID);

  gemm_mfma<true, true><<<dim3(3 * HID / 128, M / 128), 256, 0, stream>>>(
      hs_h, qkv_wt, qkv_b, mixed, (int)M, 3 * HID, HID);

  transpose_v<<<dim3(S_LEN / 64, DHEAD / 64, BATCH * NHEAD), 256, 0, stream>>>(
      mixed, vtg);

  flash_attn_v4<<<dim3(S_LEN / 128, NHEAD, BATCH), 256, 0, stream>>>(
      mixed, vtg, mask, ctx);

  gemm_mfma<false, false><<<dim3(HID / 128, M / 128), 256, 0, stream>>>(
      ctx, proj_wt, nullptr, out, (int)M, HID, HID);

  copy_bias<<<(HID + 255) / 256, 256, 0, stream>>>(proj_b, out + M * HID);
}

// Round 7
// 493.453 us; speedup vs baseline: 1.0980x; 1.0980x over previous
//
#include <hip/hip_runtime.h>
#include <cstdint>
#include <math.h>

#define S_LEN 2048
#define BATCH 2
#define HID   2048
#define NHEAD 16
#define DHEAD 128

typedef _Float16 h8 __attribute__((ext_vector_type(8)));
typedef _Float16 h4 __attribute__((ext_vector_type(4)));
typedef float f32x4 __attribute__((ext_vector_type(4)));

// async global->LDS, 16B per lane; LDS dest = wave-uniform base + lane*16
__device__ __forceinline__ void gload16(const void* g, void* l) {
  __builtin_amdgcn_global_load_lds(
      (const __attribute__((address_space(1))) unsigned int*)g,
      (__attribute__((address_space(3))) unsigned int*)l, 16, 0, 0);
}

// ---------------------------------------------------------------------------
// fp16 MFMA GEMM (unchanged since R4): C[M,N] = A[M,K] @ Bt[N,K]^T (+bias).
// ---------------------------------------------------------------------------
template <bool HAS_BIAS, bool OUT_HALF>
__global__ __launch_bounds__(256) void gemm_mfma(
    const _Float16* __restrict__ A, const _Float16* __restrict__ Bt,
    const float* __restrict__ bias, void* __restrict__ Cout, int M, int N,
    int K) {
  __shared__ _Float16 As[128 * 32];
  __shared__ _Float16 Bs[128 * 32];
  const int tid = threadIdx.x;
  const int wave = tid >> 6, lane = tid & 63;
  const int ln = lane & 15, quad = lane >> 4;
  const int wm = wave & 1, wn = wave >> 1;
  const int bm = blockIdx.y * 128, bn = blockIdx.x * 128;

  const int sr = lane >> 2;
  const int sk = (lane & 3) * 8;
  const _Float16* ga0 = A + (size_t)(bm + 32 * wave + sr) * K + sk;
  const _Float16* ga1 = A + (size_t)(bm + 32 * wave + 16 + sr) * K + sk;
  const _Float16* gb0 = Bt + (size_t)(bn + 32 * wave + sr) * K + sk;
  const _Float16* gb1 = Bt + (size_t)(bn + 32 * wave + 16 + sr) * K + sk;
  _Float16* la0 = As + 1024 * wave;
  _Float16* la1 = As + 1024 * wave + 512;
  _Float16* lb0 = Bs + 1024 * wave;
  _Float16* lb1 = Bs + 1024 * wave + 512;

  f32x4 acc[4][4];
#pragma unroll
  for (int i = 0; i < 4; i++)
#pragma unroll
    for (int j = 0; j < 4; j++) acc[i][j] = (f32x4){0.f, 0.f, 0.f, 0.f};

  for (int kt = 0; kt < K; kt += 32) {
    __syncthreads();
    gload16(ga0 + kt, la0);
    gload16(ga1 + kt, la1);
    gload16(gb0 + kt, lb0);
    gload16(gb1 + kt, lb1);
    __syncthreads();

    h8 af[4], bf[4];
#pragma unroll
    for (int mt = 0; mt < 4; mt++)
      af[mt] = *(const h8*)&As[(wm * 64 + mt * 16 + ln) * 32 + quad * 8];
#pragma unroll
    for (int nt = 0; nt < 4; nt++)
      bf[nt] = *(const h8*)&Bs[(wn * 64 + nt * 16 + ln) * 32 + quad * 8];
#pragma unroll
    for (int mt = 0; mt < 4; mt++)
#pragma unroll
      for (int nt = 0; nt < 4; nt++)
        acc[mt][nt] = __builtin_amdgcn_mfma_f32_16x16x32_f16(
            af[mt], bf[nt], acc[mt][nt], 0, 0, 0);
  }

#pragma unroll
  for (int mt = 0; mt < 4; mt++) {
#pragma unroll
    for (int r = 0; r < 4; r++) {
      const size_t row = (size_t)(bm + wm * 64 + mt * 16 + quad * 4 + r);
#pragma unroll
      for (int nt = 0; nt < 4; nt++) {
        const int col = bn + wn * 64 + nt * 16 + ln;
        float v = acc[mt][nt][r];
        if (HAS_BIAS) v += bias[col];
        if (OUT_HALF)
          ((_Float16*)Cout)[row * N + col] = (_Float16)v;
        else
          ((float*)Cout)[row * N + col] = v;
      }
    }
  }
}

__global__ __launch_bounds__(256) void transpose_cvt(
    const float* __restrict__ in, _Float16* __restrict__ out, int K, int N) {
  __shared__ float t[64][65];
  const int bn = blockIdx.x * 64, bk = blockIdx.y * 64;
  const int l = threadIdx.x & 63, g = threadIdx.x >> 6;
#pragma unroll
  for (int i = 0; i < 16; i++) {
    int r = g + 4 * i;
    t[r][l] = in[(size_t)(bk + r) * N + bn + l];
  }
  __syncthreads();
#pragma unroll
  for (int i = 0; i < 16; i++) {
    int r = g + 4 * i;
    out[(size_t)(bn + r) * K + bk + l] = (_Float16)t[l][r];
  }
}

__global__ __launch_bounds__(256) void cvt_fp16(const float* __restrict__ in,
                                                _Float16* __restrict__ out,
                                                int n4) {
  int i = blockIdx.x * blockDim.x + threadIdx.x;
  if (i < n4) {
    float4 v = ((const float4*)in)[i];
    h4 o = {(_Float16)v.x, (_Float16)v.y, (_Float16)v.z, (_Float16)v.w};
    *(h4*)&out[4 * (size_t)i] = o;
  }
}

// ---------------------------------------------------------------------------
// V pre-transpose (unchanged since R6): mixed -> Vtg [b*nh][d][s] fp16.
// ---------------------------------------------------------------------------
__global__ __launch_bounds__(256) void transpose_v(
    const _Float16* __restrict__ mixed, _Float16* __restrict__ Vtg) {
  __shared__ _Float16 T[64 * 72];
  const int sb = blockIdx.x * 64;
  const int db = blockIdx.y * 64;
  const int z = blockIdx.z;
  const int tid = threadIdx.x;

  const int r = tid >> 2, d0 = (tid & 3) * 16;
  {
    const _Float16* src =
        mixed + ((size_t)(sb + r) * (BATCH * NHEAD) + z) * 384 + 256 + db + d0;
    h8 v0 = *(const h8*)src;
    h8 v1 = *(const h8*)(src + 8);
#pragma unroll
    for (int e = 0; e < 8; e++) T[(d0 + e) * 72 + r] = v0[e];
#pragma unroll
    for (int e = 0; e < 8; e++) T[(d0 + 8 + e) * 72 + r] = v1[e];
  }
  __syncthreads();
  {
    const int dl = tid >> 2, s0 = (tid & 3) * 16;
    h8 v0 = *(const h8*)&T[dl * 72 + s0];
    h8 v1 = *(const h8*)&T[dl * 72 + s0 + 8];
    _Float16* dst = Vtg + ((size_t)z * DHEAD + db + dl) * S_LEN + sb + s0;
    *(h8*)dst = v0;
    *(h8*)(dst + 8) = v1;
  }
}

// ---------------------------------------------------------------------------
// fp16-MFMA flash attention v5. Grid (S/64, NH, B) = 1024 blocks, 256 thr.
// R7 change: OCCUPANCY. R6 was latency-bound (Mfma 7%, VALU 13%, occ 6.3%,
// no pipe >20% busy). Shrink to Q-tile 64 (16 rows/wave) + K-tile 32:
// LDS 54272 -> 24064 B, VGPR ~140 -> ~90 => 5 blocks/CU (20 waves, was 8).
// Keeps R6's reg-Q, pre-transposed global V, no-max softmax.
// Strides: Ks 136 (16-lane bank-distinct), Vt/St 40 (gcd(10,32)=2 -> 16
// distinct banks, b128 16B-aligned: 80B multiple of 16).
// ---------------------------------------------------------------------------
__global__ __launch_bounds__(256) void flash_attn_v5(
    const _Float16* __restrict__ mixed, const _Float16* __restrict__ Vtg,
    const unsigned char* __restrict__ mask, _Float16* __restrict__ ctx) {
  const int qt = (int)gridDim.x - 1 - (int)blockIdx.x;  // big blocks first
  const int h = blockIdx.y, b = blockIdx.z;
  const int qb = qt * 64;
  const int tid = threadIdx.x;
  const int wave = tid >> 6, lane = tid & 63;
  const int ln = lane & 15, quad = lane >> 4;

  __shared__ _Float16 Ks[32 * 136];    //  8704 B
  __shared__ _Float16 Vt[128 * 40];    // 10240 B  [d][k]
  __shared__ _Float16 St[4][16 * 40];  //  5120 B  per-wave P [m=16][k=32]

  const size_t RS = (size_t)BATCH * NHEAD * 384;  // halves per seq row
  const _Float16* base = mixed + ((size_t)b * NHEAD + h) * 384;
  const _Float16* vbase = Vtg + (size_t)(b * NHEAD + h) * DHEAD * S_LEN;
  const unsigned char* mbase = mask + (size_t)b * S_LEN * S_LEN;
  const float scale = 0.08838834764831845f;  // 1/sqrt(128)

  // ---- Q fragments -> registers (scaled). Wave owns rows qb+16w..+15 ----
  h8 qfrag[4];
  {
    const size_t row = (size_t)(qb + 16 * wave + ln);
#pragma unroll
    for (int kq = 0; kq < 4; kq++) {
      h8 v = *(const h8*)(base + row * RS + 32 * kq + 8 * quad);
#pragma unroll
      for (int j = 0; j < 8; j++) v[j] = (_Float16)((float)v[j] * scale);
      qfrag[kq] = v;
    }
  }

  f32x4 o[8];
#pragma unroll
  for (int nt = 0; nt < 8; nt++) o[nt] = (f32x4){0.f, 0.f, 0.f, 0.f};
  float lpart[4] = {0.f, 0.f, 0.f, 0.f};

  const int ntiles = 2 * qt + 2;  // K-tiles of 32

  // staging indices
  const int kr = tid >> 3, kd0 = (tid & 7) * 16;  // K: 32 rows x 128 d
  const int vd = tid >> 1, vk0 = (tid & 1) * 16;  // V: 128 d x 32 k

  for (int kt = 0; kt < ntiles; kt++) {
    const int kb = kt * 32;
    __syncthreads();  // B1: prev tile's readers done

    // ---- stage K (b128 both sides): 8 KB ----
    {
      const _Float16* src = base + (size_t)(kb + kr) * RS + 128 + kd0;
      *(h8*)&Ks[kr * 136 + kd0] = *(const h8*)src;
      *(h8*)&Ks[kr * 136 + kd0 + 8] = *(const h8*)(src + 8);
    }
    // ---- stage Vt (b128 both sides): 8 KB ----
    {
      const _Float16* src = vbase + (size_t)vd * S_LEN + kb + vk0;
      *(h8*)&Vt[vd * 40 + vk0] = *(const h8*)src;
      *(h8*)&Vt[vd * 40 + vk0 + 8] = *(const h8*)(src + 8);
    }
    __syncthreads();  // B2: tiles staged

    // mask bytes (8 per lane)
    unsigned char mreg[4][2];
#pragma unroll
    for (int r = 0; r < 4; r++)
#pragma unroll
      for (int jn = 0; jn < 2; jn++)
        mreg[r][jn] = mbase[(size_t)(qb + 16 * wave + 4 * quad + r) * S_LEN +
                            kb + 16 * jn + ln];

    // ---- QK^T: 2 n-frags x 4 d-steps = 8 MFMA ----
    f32x4 s[2];
    s[0] = (f32x4){0.f, 0.f, 0.f, 0.f};
    s[1] = (f32x4){0.f, 0.f, 0.f, 0.f};
#pragma unroll
    for (int kq = 0; kq < 4; kq++) {
#pragma unroll
      for (int jn = 0; jn < 2; jn++) {
        h8 bk = *(const h8*)&Ks[(16 * jn + ln) * 136 + 32 * kq + 8 * quad];
        s[jn] = __builtin_amdgcn_mfma_f32_16x16x32_f16(qfrag[kq], bk, s[jn], 0,
                                                       0, 0);
      }
    }

    // ---- no-max softmax ----
#pragma unroll
    for (int jn = 0; jn < 2; jn++)
#pragma unroll
      for (int r = 0; r < 4; r++) {
        const int grow = qb + 16 * wave + 4 * quad + r;
        const int gcol = kb + 16 * jn + ln;
        const float sv = ((gcol > grow) || mreg[r][jn]) ? -10000.0f : s[jn][r];
        const float p = __expf(sv);
        lpart[r] += p;
        St[wave][(4 * quad + r) * 40 + 16 * jn + ln] = (_Float16)p;
      }
    __threadfence_block();

    // ---- PV: single k=32 step, 8 MFMA ----
    {
      h8 ap = *(const h8*)&St[wave][ln * 40 + 8 * quad];
#pragma unroll
      for (int nt = 0; nt < 8; nt++) {
        h8 bv = *(const h8*)&Vt[(16 * nt + ln) * 40 + 8 * quad];
        o[nt] =
            __builtin_amdgcn_mfma_f32_16x16x32_f16(ap, bv, o[nt], 0, 0, 0);
      }
    }
  }

  // ---- epilogue: single l reduction, normalize, write fp16 ctx ----
#pragma unroll
  for (int r = 0; r < 4; r++) {
    float l = lpart[r];
#pragma unroll
    for (int off = 8; off >= 1; off >>= 1) l += __shfl_xor(l, off, 16);
    const float inv_l = 1.0f / l;
    const size_t row_g = (size_t)(qb + 16 * wave + 4 * quad + r);
    _Float16* dst = ctx + (row_g * BATCH + b) * HID + h * DHEAD;
#pragma unroll
    for (int nt = 0; nt < 8; nt++)
      dst[16 * nt + ln] = (_Float16)(o[nt][r] * inv_l);
  }
}

__global__ void copy_bias(const float* __restrict__ src,
                          float* __restrict__ dst) {
  int i = blockIdx.x * blockDim.x + threadIdx.x;
  if (i < HID) dst[i] = src[i];
}

extern "C" void kernel_launch(void* const* d_in, const int* in_sizes, int n_in,
                              void* d_out, int out_size, void* d_ws,
                              size_t ws_size, hipStream_t stream) {
  (void)in_sizes;
  (void)n_in;
  const float* hs = (const float*)d_in[0];
  const unsigned char* mask = (const unsigned char*)d_in[1];
  const float* qkv_w = (const float*)d_in[2];
  const float* qkv_b = (const float*)d_in[3];
  const float* proj_w = (const float*)d_in[4];
  const float* proj_b = (const float*)d_in[5];
  float* out = (float*)d_out;

  const size_t M = (size_t)S_LEN * BATCH;
  const size_t mixed_e = M * 3 * HID;
  const size_t qkvwt_e = (size_t)3 * HID * HID;
  const size_t hsh_e = M * HID;
  const size_t projwt_e = (size_t)HID * HID;
  const size_t ctx_e = M * HID;
  const size_t vtg_e = (size_t)BATCH * NHEAD * DHEAD * S_LEN;
  const size_t need =
      (mixed_e + qkvwt_e + hsh_e + projwt_e + ctx_e + vtg_e) * sizeof(_Float16);
  if (ws_size < need) return;

  _Float16* mixed = (_Float16*)d_ws;
  _Float16* qkv_wt = mixed + mixed_e;
  _Float16* hs_h = qkv_wt + qkvwt_e;
  _Float16* proj_wt = hs_h + hsh_e;
  _Float16* ctx = proj_wt + projwt_e;
  _Float16* vtg = ctx + ctx_e;

  cvt_fp16<<<(int)(hsh_e / 4 / 256), 256, 0, stream>>>(hs, hs_h,
                                                       (int)(hsh_e / 4));
  transpose_cvt<<<dim3(3 * HID / 64, HID / 64), 256, 0, stream>>>(
      qkv_w, qkv_wt, HID, 3 * HID);
  transpose_cvt<<<dim3(HID / 64, HID / 64), 256, 0, stream>>>(
      proj_w, proj_wt, HID, HID);

  gemm_mfma<true, true><<<dim3(3 * HID / 128, M / 128), 256, 0, stream>>>(
      hs_h, qkv_wt, qkv_b, mixed, (int)M, 3 * HID, HID);

  transpose_v<<<dim3(S_LEN / 64, DHEAD / 64, BATCH * NHEAD), 256, 0, stream>>>(
      mixed, vtg);

  flash_attn_v5<<<dim3(S_LEN / 64, NHEAD, BATCH), 256, 0, stream>>>(
      mixed, vtg, mask, ctx);

  gemm_mfma<false, false><<<dim3(HID / 128, M / 128), 256, 0, stream>>>(
      ctx, proj_wt, nullptr, out, (int)M, HID, HID);

  copy_bias<<<(HID + 255) / 256, 256, 0, stream>>>(proj_b, out + M * HID);
}